// Round 11
// baseline (533.005 us; speedup 1.0000x reference)
//
#include <hip/hip_runtime.h>
#include <math.h>

// Problem constants: B=8, H=W=56, C=512, N=3136, c4=128, HEADS=8, hd=64, SR=2
// kv sequence length = 14*14 = 196 (padded to 224 for attention)

typedef _Float16 half8 __attribute__((ext_vector_type(8)));
typedef float f32x4 __attribute__((ext_vector_type(4)));

// ---------------- workspace layout (offsets in halves; all 16B-aligned) ----
static const size_t OFF_X16  = 0;
static const size_t OFF_Q16  = 12845056;
static const size_t OFF_CAT  = 25690112;
static const size_t OFF_R16  = 41746432;
static const size_t OFF_PAD  = 44957696;
static const size_t OFF_DWTB = 48644096;
static const size_t OFF_QRW  = 51855360;
static const size_t OFF_LN16 = 55066624;
static const size_t OFF_KV16 = 55869440;
static const size_t OFF_WT   = 57475072;
static const size_t OFF_KT   = 59834368;
static const size_t OFF_KVW  = 61145088;
static const size_t OFF_PW   = 61669376;
static const size_t OFF_VT   = 62062592;
static const size_t OFF_PART = 62980096;
// total = 75,825,152 halves = 151.7 MB

#define BN_RSQ 0.9999950000374997f
#define SCL2   0.1803368801111204f   /* 0.125 * log2(e) */
#define PART_STRIDE 3211264          /* 6272*512 floats per conv partial */
#define KVE_STRIDE  802816           /* 1568*512 floats per kve partial */

__device__ __forceinline__ void async_copy16(const _Float16* g, _Float16* l) {
    __builtin_amdgcn_global_load_lds(
        (const __attribute__((address_space(1))) void*)g,
        (__attribute__((address_space(3))) void*)l, 16, 0, 0);
}

// counted-vmcnt barriers (T4) fused in one asm (compiler can't inject vmcnt(0))
#define WAIT4_BARRIER() asm volatile("s_waitcnt vmcnt(4)\n\ts_barrier" ::: "memory")
#define WAIT3_BARRIER() asm volatile("s_waitcnt vmcnt(3)\n\ts_barrier" ::: "memory")
#define WAIT0_BARRIER() asm volatile("s_waitcnt vmcnt(0)\n\ts_barrier" ::: "memory")

// =====================================================================
// THIN 4-wave MFMA fp16 NT GEMM (128x128, BK=32) — for small GEMMs.
// ALOAD: 0 plain row-major (lda), 2 kve 2x2 stride-2 (lda = W row-stride)
// EPI:   3 = raw fp32 partial at blockIdx.z*KVE_STRIDE (split-K)
//        5 = fused kv/vt: n0<512 -> +bias->fp16 kv16; n0>=512 -> V^T scatter
// =====================================================================
template <int ALOAD, int EPI>
__global__ __launch_bounds__(256) void gemm16(
    const _Float16* __restrict__ A, const _Float16* __restrict__ W,
    void* __restrict__ outp, int M, int K, int lda, int ldc,
    const float* __restrict__ bias, void* __restrict__ outp2)
{
    __shared__ _Float16 sA[3][128 * 32];
    __shared__ _Float16 sB[3][128 * 32];
    const int t = threadIdx.x;
    const int lane = t & 63, wid = t >> 6;

    int bx = blockIdx.x, by = blockIdx.y;
    const int m0 = bx * 128, n0 = by * 128;
    const int kbase = blockIdx.z * K;

    const int sr = wid * 16 + (lane >> 2);
    const int sc = (lane & 3) * 8;
    const int stA0 = wid * 512;
    const int stA1 = 2048 + wid * 512;

    const _Float16 *aP0, *aP1;
    if constexpr (ALOAD == 0) {
        int r0 = m0 + sr;      if (r0 > M - 1) r0 = M - 1;
        int r1 = m0 + 64 + sr; if (r1 > M - 1) r1 = M - 1;
        aP0 = A + (size_t)r0 * lda + sc;
        aP1 = A + (size_t)r1 * lda + sc;
    } else {
        int m_ = m0 + sr; if (m_ > M - 1) m_ = M - 1;
        int b_ = m_ / 196, rem = m_ - b_ * 196, i_ = rem / 14, j_ = rem - i_ * 14;
        aP0 = A + ((size_t)(b_ * 784 + 2 * i_ * 28 + 2 * j_)) * 512 + sc;
        m_ = m0 + 64 + sr; if (m_ > M - 1) m_ = M - 1;
        b_ = m_ / 196; rem = m_ - b_ * 196; i_ = rem / 14; j_ = rem - i_ * 14;
        aP1 = A + ((size_t)(b_ * 784 + 2 * i_ * 28 + 2 * j_)) * 512 + sc;
    }
    const int ldw = (ALOAD == 2) ? lda : K;
    const _Float16* bP0 = W + (size_t)(n0 + sr) * ldw + sc;
    const _Float16* bP1 = W + (size_t)(n0 + 64 + sr) * ldw + sc;

    const int mw = wid & 1, nw = wid >> 1;
    const int pAoff = (mw * 64 + (lane & 15)) * 32 + (lane >> 4) * 8;
    const int pBoff = (nw * 64 + (lane & 15)) * 32 + (lane >> 4) * 8;

    f32x4 acc[4][4];
#pragma unroll
    for (int i = 0; i < 4; ++i)
#pragma unroll
        for (int j = 0; j < 4; ++j) acc[i][j] = (f32x4)(0.0f);

    auto aoff_of = [&](int k) -> int {
        if constexpr (ALOAD == 0) {
            return k;
        } else {
            int sub = k >> 9; int ky = sub >> 1, kx = sub & 1;
            return (ky * 28 + kx) * 512 + (k & 511);
        }
    };
    auto stage = [&](int ti, int buf) {
        int k = kbase + ti * 32;
        int aOff = aoff_of(k);
        async_copy16(aP0 + aOff, &sA[buf][stA0]);
        async_copy16(aP1 + aOff, &sA[buf][stA1]);
        async_copy16(bP0 + k, &sB[buf][stA0]);
        async_copy16(bP1 + k, &sB[buf][stA1]);
    };

    const int nt = K >> 5;
    stage(0, 0);
    if (nt > 1) { stage(1, 1); WAIT4_BARRIER(); }
    else        { WAIT0_BARRIER(); }

    int cur = 0;
    for (int i = 0; i < nt; ++i) {
        const _Float16* pA = &sA[cur][0] + pAoff;
        const _Float16* pB = &sB[cur][0] + pBoff;
        half8 aF[4], bF[4];
#pragma unroll
        for (int u = 0; u < 4; ++u) aF[u] = *(const half8*)(pA + u * 512);
#pragma unroll
        for (int u = 0; u < 4; ++u) bF[u] = *(const half8*)(pB + u * 512);

        const bool st = (i + 2 < nt);
        if (st) {
            int nb = cur + 2; if (nb >= 3) nb -= 3;
            stage(i + 2, nb);
        }
#pragma unroll
        for (int u = 0; u < 4; ++u)
#pragma unroll
            for (int j = 0; j < 4; ++j)
                acc[u][j] = __builtin_amdgcn_mfma_f32_16x16x32_f16(
                    aF[u], bF[j], acc[u][j], 0, 0, 0);

        if (i + 1 < nt) {
            if (st) WAIT4_BARRIER();
            else    WAIT0_BARRIER();
        }
        ++cur; if (cur == 3) cur = 0;
    }

    const int orow = m0 + mw * 64 + (lane >> 4) * 4;
    const int ocol = n0 + nw * 64 + (lane & 15);
#pragma unroll
    for (int j = 0; j < 4; ++j) {
        int col = ocol + j * 16;
        float bv = 0.0f;
        if constexpr (EPI == 5) bv = bias[col];
#pragma unroll
        for (int i = 0; i < 4; ++i) {
#pragma unroll
            for (int r = 0; r < 4; ++r) {
                int row = orow + i * 16 + r;
                if (row >= M) continue;
                float v = acc[i][j][r] + bv;
                if constexpr (EPI == 3) {
                    ((float*)outp)[(size_t)blockIdx.z * KVE_STRIDE
                                   + (size_t)row * ldc + col] = v;
                } else {   // EPI == 5
                    if (n0 >= 512) {   // V^T scatter: vt[((b*8+h)*64+d)*224+m]
                        int hd_ = col - 512;
                        int h_ = hd_ >> 6, d_ = hd_ & 63;
                        int b_ = row / 196, m_ = row - b_ * 196;
                        ((_Float16*)outp2)[((size_t)((b_ * 8 + h_) * 64 + d_)) * 224
                                           + m_] = (_Float16)v;
                    } else {
                        ((_Float16*)outp)[(size_t)row * ldc + col] = (_Float16)v;
                    }
                }
            }
        }
    }
}

// =====================================================================
// 8-WAVE 256x128 MFMA fp16 NT GEMM (BK=32, 512 threads) — R9 proven form
// (linear LDS; the T2 granule swizzle was a measured null: conflict count
// bit-identical, 8 cyc is the b128 wave64 floor). 3-buffer, vmcnt(3).
// Waves 4(M)x2(N), per-wave 64x64 (8 ds_read feed 16 MFMA).
// EPI: 0 = +bias -> fp32 nontemporal (proj out)
//      4 = fused q/r: n0<512 -> +bias->fp16 q16; n0>=512 -> BN+ReLU->r16
// =====================================================================
template <int EPI>
__global__ __launch_bounds__(512, 4) void gemm256(
    const _Float16* __restrict__ A, const _Float16* __restrict__ W,
    void* __restrict__ outp, int M, int K, int lda, int ldc,
    const float* __restrict__ bias, const float* __restrict__ bng,
    const float* __restrict__ bnb, const float* __restrict__ bias2,
    void* __restrict__ outp2)
{
    __shared__ _Float16 sA[3][256 * 32];
    __shared__ _Float16 sB[3][128 * 32];
    const int t = threadIdx.x;
    const int lane = t & 63, wid = t >> 6;   // 0..7

    int bx = blockIdx.x, by = blockIdx.y;
    {
        int nwg = gridDim.x * gridDim.y;
        if ((nwg & 7) == 0) {            // bijective XCD-chunked remap
            int orig = by * gridDim.x + bx;
            int cs = nwg >> 3;
            int wg = (orig & 7) * cs + (orig >> 3);
            by = wg % gridDim.y;
            bx = wg / gridDim.y;
        }
    }
    const int m0 = bx * 256, n0 = by * 128;

    const int sr = wid * 16 + (lane >> 2);   // staging row
    const int sc = (lane & 3) * 8;           // staging col (halves)
    const int stO = wid * 512;

    int r0 = m0 + sr;       if (r0 > M - 1) r0 = M - 1;
    int r1 = m0 + 128 + sr; if (r1 > M - 1) r1 = M - 1;
    const _Float16* aP0 = A + (size_t)r0 * lda + sc;
    const _Float16* aP1 = A + (size_t)r1 * lda + sc;
    const _Float16* bP = W + (size_t)(n0 + sr) * K + sc;

    const int mw = wid & 3, nw = wid >> 2;   // 4(M) x 2(N)
    const int pAoff = (mw * 64 + (lane & 15)) * 32 + (lane >> 4) * 8;
    const int pBoff = (nw * 64 + (lane & 15)) * 32 + (lane >> 4) * 8;

    f32x4 acc[4][4];
#pragma unroll
    for (int u = 0; u < 4; ++u)
#pragma unroll
        for (int v = 0; v < 4; ++v) acc[u][v] = (f32x4)(0.0f);

    auto stage = [&](int ti, int buf) {
        int k = ti * 32;
        async_copy16(aP0 + k, &sA[buf][stO]);
        async_copy16(aP1 + k, &sA[buf][4096 + stO]);
        async_copy16(bP + k, &sB[buf][stO]);
    };

    const int nt = K >> 5;
    stage(0, 0);
    stage(1, 1);
    WAIT3_BARRIER();

    int cur = 0;
    for (int i = 0; i < nt; ++i) {
        const _Float16* pA = &sA[cur][0] + pAoff;
        const _Float16* pB = &sB[cur][0] + pBoff;
        half8 aF[4], bF[4];
#pragma unroll
        for (int u = 0; u < 4; ++u) aF[u] = *(const half8*)(pA + u * 512);
#pragma unroll
        for (int v = 0; v < 4; ++v) bF[v] = *(const half8*)(pB + v * 512);

        const bool st = (i + 2 < nt);
        if (st) {
            int nb = cur + 2; if (nb >= 3) nb -= 3;
            stage(i + 2, nb);
        }
#pragma unroll
        for (int u = 0; u < 4; ++u)
#pragma unroll
            for (int v = 0; v < 4; ++v)
                acc[u][v] = __builtin_amdgcn_mfma_f32_16x16x32_f16(
                    aF[u], bF[v], acc[u][v], 0, 0, 0);

        if (i + 1 < nt) {
            if (st) WAIT3_BARRIER();
            else    WAIT0_BARRIER();
        }
        ++cur; if (cur == 3) cur = 0;
    }

    // epilogue: wave covers 64M x 64N; C/D layout col=lane&15, row=(lane>>4)*4+reg
    const int orow = m0 + mw * 64 + (lane >> 4) * 4;
    const int ocol = n0 + nw * 64 + (lane & 15);
#pragma unroll
    for (int v = 0; v < 4; ++v) {
        int col = ocol + v * 16;
        float bv, g = 0.0f, b2 = 0.0f;
        if constexpr (EPI == 4) {
            if (n0 >= 512) {           // r path (block-uniform branch)
                bv = bias2[col - 512];
                g = bng[col - 512] * BN_RSQ;
                b2 = bnb[col - 512];
            } else {
                bv = bias[col];
            }
        } else {
            bv = bias[col];
        }
#pragma unroll
        for (int u = 0; u < 4; ++u) {
#pragma unroll
            for (int r = 0; r < 4; ++r) {
                int row = orow + u * 16 + r;
                if (row >= M) continue;
                float v2 = acc[u][v][r] + bv;
                if constexpr (EPI == 0) {
                    __builtin_nontemporal_store(
                        v2, (float*)outp + (size_t)row * ldc + col);
                } else {   // EPI == 4
                    if (n0 >= 512) {
                        v2 = fmaxf(v2 * g + b2, 0.0f);
                        ((_Float16*)outp2)[(size_t)row * 128 + (col - 512)] =
                            (_Float16)v2;
                    } else {
                        ((_Float16*)outp)[(size_t)row * ldc + col] = (_Float16)v2;
                    }
                }
            }
        }
    }
}

// =====================================================================
// 8-wave 256x128 conv3x3 split-K partial GEMM — DEPTH-1 2-BUFFER probe.
// LDS 2 x 24KB = 48KB -> 3 blocks/CU = 24 waves/CU, AND capacity (768)
// exceeds grid (400) -> whole grid co-resident, zero makespan tail.
// Trade: per-iter wait is vmcnt(0) (stage for next tile drains at the
// barrier), but at 24 waves/CU the other two resident blocks' MFMA
// covers each block's drain (m114 cross-block overlap).
// grid 400 linear (25 m x 4 n x 4 z), XCD-chunked swizzle (400 = 8*50).
// =====================================================================
__global__ __launch_bounds__(512, 6) void conv_splitk(
    const _Float16* __restrict__ A, const _Float16* __restrict__ W,
    float* __restrict__ partA, float* __restrict__ partB)
{
    __shared__ _Float16 sA[2][256 * 32];
    __shared__ _Float16 sB[2][128 * 32];
    const int t = threadIdx.x;
    const int lane = t & 63, wid = t >> 6;   // 0..7

    // bijective XCD-chunked remap: 400 = 8 * 50
    int orig = blockIdx.x;
    int wg = (orig & 7) * 50 + (orig >> 3);
    int bx = wg % 25;  int c = wg / 25;    // c in 0..15
    int by = c & 3,    bz = c >> 2;

    const int m0 = bx * 256, n0 = by * 128;
    const int kbase = bz * 1152;

    const int sr = wid * 16 + (lane >> 2);
    const int sc = (lane & 3) * 8;
    const int stO = wid * 512;

    int m_ = m0 + sr; if (m_ > 6271) m_ = 6271;
    int b_ = m_ / 784, rem = m_ - b_ * 784, y_ = rem / 28, x_ = rem - y_ * 28;
    const _Float16* aP0 = A + ((size_t)(b_ * 900 + (y_ + 1) * 30 + (x_ + 1))) * 512 + sc;
    m_ = m0 + 128 + sr; if (m_ > 6271) m_ = 6271;
    b_ = m_ / 784; rem = m_ - b_ * 784; y_ = rem / 28; x_ = rem - y_ * 28;
    const _Float16* aP1 = A + ((size_t)(b_ * 900 + (y_ + 1) * 30 + (x_ + 1))) * 512 + sc;
    const _Float16* bP = W + (size_t)(n0 + sr) * 4608 + sc;

    const int mw = wid & 3, nw = wid >> 2;
    const int pAoff = (mw * 64 + (lane & 15)) * 32 + (lane >> 4) * 8;
    const int pBoff = (nw * 64 + (lane & 15)) * 32 + (lane >> 4) * 8;

    f32x4 acc[4][4];
#pragma unroll
    for (int u = 0; u < 4; ++u)
#pragma unroll
        for (int v = 0; v < 4; ++v) acc[u][v] = (f32x4)(0.0f);

    auto aoff_of = [&](int k) -> int {
        int sub = k >> 9; int s3 = sub / 3;
        int dy = s3 - 1, dx = sub - s3 * 3 - 1;
        return (dy * 30 + dx) * 512 + (k & 511);
    };
    auto stage = [&](int ti, int buf) {
        int k = kbase + ti * 32;
        int aOff = aoff_of(k);
        async_copy16(aP0 + aOff, &sA[buf][stO]);
        async_copy16(aP1 + aOff, &sA[buf][4096 + stO]);
        async_copy16(bP + k, &sB[buf][stO]);
    };

    const int nt = 36;   // 1152/32
    stage(0, 0);
    WAIT0_BARRIER();

    int cur = 0;
    for (int i = 0; i < nt; ++i) {
        if (i + 1 < nt) stage(i + 1, cur ^ 1);   // in flight during compute
        const _Float16* pA = &sA[cur][0] + pAoff;
        const _Float16* pB = &sB[cur][0] + pBoff;
        half8 aF[4], bF[4];
#pragma unroll
        for (int u = 0; u < 4; ++u) aF[u] = *(const half8*)(pA + u * 512);
#pragma unroll
        for (int v = 0; v < 4; ++v) bF[v] = *(const half8*)(pB + v * 512);
#pragma unroll
        for (int u = 0; u < 4; ++u)
#pragma unroll
            for (int v = 0; v < 4; ++v)
                acc[u][v] = __builtin_amdgcn_mfma_f32_16x16x32_f16(
                    aF[u], bF[v], acc[u][v], 0, 0, 0);
        WAIT0_BARRIER();   // next tile staged + everyone done reading cur
        cur ^= 1;
    }

    float* dst = (bz < 2) ? (partA + (size_t)bz * PART_STRIDE)
                          : (partB + (size_t)(bz - 2) * PART_STRIDE);
    const int orow = m0 + mw * 64 + (lane >> 4) * 4;
    const int ocol = n0 + nw * 64 + (lane & 15);
#pragma unroll
    for (int v = 0; v < 4; ++v) {
#pragma unroll
        for (int u = 0; u < 4; ++u) {
#pragma unroll
            for (int r = 0; r < 4; ++r) {
                int row = orow + u * 16 + r;
                if (row < 6272)
                    dst[(size_t)row * 512 + ocol + v * 16] = acc[u][v][r];
            }
        }
    }
}

// =====================================================================
// FUSED conv epilogue + Haar IDWT. One block per output pixel (6272),
// 128 threads. Writes dwtb16 + IDWT -> cat cols 512..639 (nt).
// =====================================================================
__global__ __launch_bounds__(128) void conv_epi_idwt(
    const float* __restrict__ pA, const float* __restrict__ pB,
    _Float16* __restrict__ dwtb, _Float16* __restrict__ cat,
    const float* __restrict__ bias, const float* __restrict__ bng,
    const float* __restrict__ bnb)
{
    int p = blockIdx.x;              // b*784 + i*28 + j
    int b = p / 784; int rem = p - b * 784;
    int i = rem / 28;  int j = rem - i * 28;
    int c = threadIdx.x;
    size_t base = (size_t)p * 512;
    _Float16 g16[4];
#pragma unroll
    for (int g = 0; g < 4; ++g) {
        int ch = g * 128 + c;
        float s = (pA[base + ch] + pA[PART_STRIDE + base + ch])
                + (pB[base + ch] + pB[PART_STRIDE + base + ch]);
        float v = (s + bias[ch]) * (bng[ch] * BN_RSQ) + bnb[ch];
        g16[g] = (_Float16)fmaxf(v, 0.0f);
        dwtb[base + ch] = g16[g];
    }
    _Float16 ll = g16[0], hl = g16[1], lh = g16[2], hh = g16[3];
    _Float16 h = (_Float16)0.5f;
    _Float16 p1 = (((ll - hl) - lh) + hh) * h;
    _Float16 p2 = (((ll - hl) + lh) - hh) * h;
    _Float16 p3 = (((ll + hl) - lh) - hh) * h;
    _Float16 p4 = (((ll + hl) + lh) + hh) * h;
    int y = 2 * i, x = 2 * j;
    size_t rb = (size_t)b * 3136;
    __builtin_nontemporal_store(p1, &cat[(rb + (size_t)y * 56 + x) * 640 + 512 + c]);
    __builtin_nontemporal_store(p3, &cat[(rb + (size_t)y * 56 + x + 1) * 640 + 512 + c]);
    __builtin_nontemporal_store(p2, &cat[(rb + (size_t)(y + 1) * 56 + x) * 640 + 512 + c]);
    __builtin_nontemporal_store(p4, &cat[(rb + (size_t)(y + 1) * 56 + x + 1) * 640 + 512 + c]);
}

// =====================================================================
// MEGA-PREP v2: coalesced transposes (thread-per-(n,ci), contiguous
// reads, per-sub coalesced writes) + weight cvts + zero-fills + x cvt.
//  [0,128)       q_w cvt -> qrw16             (32768 x8)
//  [128,160)     reduce_w cvt -> qrw16+262144 (8192 x8)
//  [160,416)     kv_w cvt -> kvw16            (65536 x8)
//  [416,576)     proj_w cvt -> pw16           (40960 x8)
//  [576,1600)    filter transpose (512n x 512ci, 9 elems/thread)
//  [1600,2624)   kve transpose    (512n x 512ci, float4/thread)
//  [2624,4424)   zero pad16                   (460800 x8)
//  [4424,4872)   zero vt16                    (114688 x8)
//  [4872,11144)  x cvt -> x16                 (1605632 x8)
// =====================================================================
__device__ __forceinline__ void cvt8_at(
    const float* __restrict__ s, _Float16* __restrict__ d, int i)
{
    const float4* sp = (const float4*)(s + (size_t)i * 8);
    float4 a = sp[0], b = sp[1];
    half8 h;
    h[0] = (_Float16)a.x; h[1] = (_Float16)a.y; h[2] = (_Float16)a.z; h[3] = (_Float16)a.w;
    h[4] = (_Float16)b.x; h[5] = (_Float16)b.y; h[6] = (_Float16)b.z; h[7] = (_Float16)b.w;
    *(half8*)(d + (size_t)i * 8) = h;
}

__global__ __launch_bounds__(256) void prep_kernel(
    const float* __restrict__ qw, const float* __restrict__ rw,
    const float* __restrict__ kvw, const float* __restrict__ pw,
    const float* __restrict__ fw, const float* __restrict__ kw,
    const float* __restrict__ x,
    _Float16* __restrict__ qrw16, _Float16* __restrict__ kvw16,
    _Float16* __restrict__ pw16, _Float16* __restrict__ wT,
    _Float16* __restrict__ kT, _Float16* __restrict__ pad,
    _Float16* __restrict__ vt, _Float16* __restrict__ x16)
{
    int bid = blockIdx.x, tid = threadIdx.x;
    if (bid < 128) {
        cvt8_at(qw, qrw16, bid * 256 + tid);
    } else if (bid < 160) {
        cvt8_at(rw, qrw16 + 262144, (bid - 128) * 256 + tid);
    } else if (bid < 416) {
        cvt8_at(kvw, kvw16, (bid - 160) * 256 + tid);
    } else if (bid < 576) {
        cvt8_at(pw, pw16, (bid - 416) * 256 + tid);
    } else if (bid < 1600) {
        // filter transpose: wT[n*4608 + s*512 + ci] = fw[n*4608 + ci*9 + s]
        int id = (bid - 576) * 256 + tid;      // 262144 = 512n x 512ci
        int n = id >> 9, ci = id & 511;
        const float* src = fw + (size_t)n * 4608 + ci * 9;
        _Float16* dstp = wT + (size_t)n * 4608 + ci;
#pragma unroll
        for (int s = 0; s < 9; ++s)
            dstp[s * 512] = (_Float16)src[s];
    } else if (bid < 2624) {
        // kve transpose: kT[n*2048 + s*512 + ci] = kw[n*2048 + ci*4 + s]
        int id = (bid - 1600) * 256 + tid;     // 262144
        int n = id >> 9, ci = id & 511;
        float4 kv4 = *(const float4*)(kw + ((size_t)n << 11) + (ci << 2));
        _Float16* dstp = kT + ((size_t)n << 11) + ci;
        dstp[0]    = (_Float16)kv4.x;
        dstp[512]  = (_Float16)kv4.y;
        dstp[1024] = (_Float16)kv4.z;
        dstp[1536] = (_Float16)kv4.w;
    } else if (bid < 4424) {
        int i = (bid - 2624) * 256 + tid;
        *(float4*)(pad + (size_t)i * 8) = make_float4(0.f, 0.f, 0.f, 0.f);
    } else if (bid < 4872) {
        int i = (bid - 4424) * 256 + tid;
        *(float4*)(vt + (size_t)i * 8) = make_float4(0.f, 0.f, 0.f, 0.f);
    } else {
        cvt8_at(x, x16, (bid - 4872) * 256 + tid);
    }
}

// =====================================================================
// Haar DWT: rbuf16 (B,56,56,128 NHWC fp16) -> padded (B,30,30,512 NHWC fp16)
// =====================================================================
__global__ __launch_bounds__(128) void dwt_kernel(
    const _Float16* __restrict__ r, _Float16* __restrict__ pad)
{
    int bid = blockIdx.x;            // b*784 + i*28 + j
    int b = bid / 784; int rem = bid - b * 784;
    int i = rem / 28;  int j = rem - i * 28;
    int c = threadIdx.x;
    int y = 2 * i, x = 2 * j;
    size_t base = (size_t)b * 3136;
    _Float16 f1 = r[(base + (size_t)y * 56 + x) * 128 + c];
    _Float16 f2 = r[(base + (size_t)(y + 1) * 56 + x) * 128 + c];
    _Float16 f3 = r[(base + (size_t)y * 56 + (x + 1)) * 128 + c];
    _Float16 f4 = r[(base + (size_t)(y + 1) * 56 + (x + 1)) * 128 + c];
    _Float16 h = (_Float16)0.5f;
    _Float16 x1 = f1 * h, x2 = f2 * h, x3 = f3 * h, x4 = f4 * h;
    _Float16 ll = ((x1 + x2) + x3) + x4;
    _Float16 hl = (((-x1) - x2) + x3) + x4;
    _Float16 lh = (((-x1) + x2) - x3) + x4;
    _Float16 hh = ((x1 - x2) - x3) + x4;
    size_t ob = ((size_t)b * 900 + (size_t)(i + 1) * 30 + (j + 1)) * 512;
    pad[ob + c]       = ll;
    pad[ob + 128 + c] = hl;
    pad[ob + 256 + c] = lh;
    pad[ob + 384 + c] = hh;
}

// =====================================================================
// LayerNorm over C=512, fused kve split-K reduction. One wave per row.
// =====================================================================
__global__ __launch_bounds__(256) void ln_kernel(
    const float* __restrict__ part, _Float16* __restrict__ o,
    const float* __restrict__ g, const float* __restrict__ bta,
    const float* __restrict__ kvb)
{
    int wave = threadIdx.x >> 6;
    int lane = threadIdx.x & 63;
    int row = blockIdx.x * 4 + wave;            // 392*4 = 1568
    int c = lane * 8;
    const float* rp = part + (size_t)row * 512 + c;
    float v[8];
#pragma unroll
    for (int i = 0; i < 8; i += 4) {
        float4 a0 = *(const float4*)(rp + i);
        float4 a1 = *(const float4*)(rp + KVE_STRIDE + i);
        float4 a2 = *(const float4*)(rp + 2 * KVE_STRIDE + i);
        float4 a3 = *(const float4*)(rp + 3 * KVE_STRIDE + i);
        v[i + 0] = (a0.x + a1.x) + (a2.x + a3.x) + kvb[c + i + 0];
        v[i + 1] = (a0.y + a1.y) + (a2.y + a3.y) + kvb[c + i + 1];
        v[i + 2] = (a0.z + a1.z) + (a2.z + a3.z) + kvb[c + i + 2];
        v[i + 3] = (a0.w + a1.w) + (a2.w + a3.w) + kvb[c + i + 3];
    }
    float s = ((v[0] + v[1]) + (v[2] + v[3])) + ((v[4] + v[5]) + (v[6] + v[7]));
#pragma unroll
    for (int off = 32; off; off >>= 1) s += __shfl_xor(s, off);
    float mu = s * (1.0f / 512.0f);
    float sq = 0.0f;
#pragma unroll
    for (int i = 0; i < 8; ++i) { v[i] -= mu; sq += v[i] * v[i]; }
#pragma unroll
    for (int off = 32; off; off >>= 1) sq += __shfl_xor(sq, off);
    float inv = 1.0f / sqrtf(sq * (1.0f / 512.0f) + 1e-5f);
    half8 hv;
#pragma unroll
    for (int i = 0; i < 8; ++i) hv[i] = (_Float16)(v[i] * inv * g[c + i] + bta[c + i]);
    *(half8*)(o + (size_t)row * 512 + c) = hv;
}

// =====================================================================
// MFMA flash attention. Block = (b, h, 64 q-rows); 4 waves x 16 q-rows.
// Unnormalized softmax (scores tiny), one reduction at the end.
// s_setprio(1) around MFMA clusters (T5).
// =====================================================================
__global__ __launch_bounds__(256) void attn_mfma(
    const _Float16* __restrict__ q, const _Float16* __restrict__ kv,
    const _Float16* __restrict__ vt, _Float16* __restrict__ cat)
{
    __shared__ _Float16 sK[64][72];    // K[m][d]
    __shared__ _Float16 sVT[64][72];   // V^T[d][m-chunk]
    __shared__ _Float16 sP[4][16][40]; // per-wave P round-trip
    int bid = blockIdx.x;
    int qt = bid % 49;
    int h  = (bid / 49) & 7;
    int b  = bid / 392;
    int n0 = qt * 64;
    int t = threadIdx.x, lane = t & 63, wid = t >> 6;
    int quad = lane >> 4, l16 = lane & 15;

    const _Float16* qp = q + ((size_t)(b * 3136 + n0 + wid * 16 + l16)) * 512
                           + h * 64 + quad * 8;
    half8 aQ0 = *(const half8*)qp;
    half8 aQ1 = *(const half8*)(qp + 32);

    f32x4 oacc[4];
#pragma unroll
    for (int i = 0; i < 4; ++i) oacc[i] = (f32x4)(0.0f);
    float lsum[4] = {0.f, 0.f, 0.f, 0.f};

    const _Float16* vtb = vt + ((size_t)((b * 8 + h) * 64)) * 224;

    for (int c0 = 0; c0 < 224; c0 += 64) {
        __syncthreads();
#pragma unroll
        for (int it = 0; it < 2; ++it) {
            int slot = t + 256 * it;
            int row = slot >> 3, c8 = (slot & 7) * 8;
            int m = c0 + row; if (m > 195) m = 195;
            *(half8*)&sK[row][c8] =
                *(const half8*)(kv + ((size_t)(b * 196 + m)) * 1024 + h * 64 + c8);
        }
#pragma unroll
        for (int it = 0; it < 2; ++it) {
            int slot = t + 256 * it;
            int row = slot >> 3, c8 = (slot & 7) * 8;
            *(half8*)&sVT[row][c8] =
                *(const half8*)(vtb + (size_t)row * 224 + c0 + c8);
        }
        __syncthreads();

#pragma unroll
        for (int sc = 0; sc < 64; sc += 32) {
            half8 bk00 = *(const half8*)&sK[sc + l16][quad * 8];
            half8 bk01 = *(const half8*)&sK[sc + l16][32 + quad * 8];
            half8 bk10 = *(const half8*)&sK[sc + 16 + l16][quad * 8];
            half8 bk11 = *(const half8*)&sK[sc + 16 + l16][32 + quad * 8];
            f32x4 s0 = (f32x4)(0.0f), s1 = (f32x4)(0.0f);
            __builtin_amdgcn_s_setprio(1);
            s0 = __builtin_amdgcn_mfma_f32_16x16x32_f16(aQ0, bk00, s0, 0, 0, 0);
            s0 = __builtin_amdgcn_mfma_f32_16x16x32_f16(aQ1, bk01, s0, 0, 0, 0);
            s1 = __builtin_amdgcn_mfma_f32_16x16x32_f16(aQ0, bk10, s1, 0, 0, 0);
            s1 = __builtin_amdgcn_mfma_f32_16x16x32_f16(aQ1, bk11, s1, 0, 0, 0);
            __builtin_amdgcn_s_setprio(0);

            int col0 = c0 + sc + l16;
            float msk0 = (col0 < 196) ? 0.0f : -INFINITY;
            float msk1 = (col0 + 16 < 196) ? 0.0f : -INFINITY;
            float p0[4], p1[4];
#pragma unroll
            for (int r = 0; r < 4; ++r) {
                p0[r] = exp2f(s0[r] * SCL2 + msk0);
                p1[r] = exp2f(s1[r] * SCL2 + msk1);
                lsum[r] += p0[r] + p1[r];
            }
#pragma unroll
            for (int r = 0; r < 4; ++r) {
                sP[wid][quad * 4 + r][l16]      = (_Float16)p0[r];
                sP[wid][quad * 4 + r][16 + l16] = (_Float16)p1[r];
            }
            half8 aP = *(const half8*)&sP[wid][l16][quad * 8];
            half8 bv0 = *(const half8*)&sVT[l16][sc + quad * 8];
            half8 bv1 = *(const half8*)&sVT[16 + l16][sc + quad * 8];
            half8 bv2 = *(const half8*)&sVT[32 + l16][sc + quad * 8];
            half8 bv3 = *(const half8*)&sVT[48 + l16][sc + quad * 8];
            __builtin_amdgcn_s_setprio(1);
            oacc[0] = __builtin_amdgcn_mfma_f32_16x16x32_f16(aP, bv0, oacc[0], 0, 0, 0);
            oacc[1] = __builtin_amdgcn_mfma_f32_16x16x32_f16(aP, bv1, oacc[1], 0, 0, 0);
            oacc[2] = __builtin_amdgcn_mfma_f32_16x16x32_f16(aP, bv2, oacc[2], 0, 0, 0);
            oacc[3] = __builtin_amdgcn_mfma_f32_16x16x32_f16(aP, bv3, oacc[3], 0, 0, 0);
            __builtin_amdgcn_s_setprio(0);
        }
    }

    float inv[4];
#pragma unroll
    for (int r = 0; r < 4; ++r) {
        float s = lsum[r];
        s += __shfl_xor(s, 1);
        s += __shfl_xor(s, 2);
        s += __shfl_xor(s, 4);
        s += __shfl_xor(s, 8);
        inv[r] = 1.0f / s;
    }
#pragma unroll
    for (int r = 0; r < 4; ++r) {
        size_t rowoff = ((size_t)(b * 3136 + n0 + wid * 16 + quad * 4 + r)) * 640
                        + h * 64 + l16;
#pragma unroll
        for (int tv = 0; tv < 4; ++tv)
            cat[rowoff + tv * 16] = (_Float16)(oacc[tv][r] * inv[r]);
    }
}

// =====================================================================
extern "C" void kernel_launch(void* const* d_in, const int* in_sizes, int n_in,
                              void* d_out, int out_size, void* d_ws, size_t ws_size,
                              hipStream_t stream)
{
    const float* x           = (const float*)d_in[0];
    const float* reduce_w    = (const float*)d_in[3];
    const float* reduce_b    = (const float*)d_in[4];
    const float* reduce_g    = (const float*)d_in[5];
    const float* reduce_beta = (const float*)d_in[6];
    const float* filter_w    = (const float*)d_in[7];
    const float* filter_b    = (const float*)d_in[8];
    const float* filter_g    = (const float*)d_in[9];
    const float* filter_beta = (const float*)d_in[10];
    const float* q_w         = (const float*)d_in[11];
    const float* q_b         = (const float*)d_in[12];
    const float* ln_g        = (const float*)d_in[13];
    const float* ln_b        = (const float*)d_in[14];
    const float* kv_w        = (const float*)d_in[15];
    const float* kv_b        = (const float*)d_in[16];
    const float* kve_w       = (const float*)d_in[17];
    const float* kve_b       = (const float*)d_in[18];
    const float* proj_w      = (const float*)d_in[19];
    const float* proj_b      = (const float*)d_in[20];
    float* out = (float*)d_out;
    _Float16* hws = (_Float16*)d_ws;

    _Float16* x16    = hws + OFF_X16;
    _Float16* q16    = hws + OFF_Q16;
    _Float16* cat16  = hws + OFF_CAT;
    _Float16* r16    = hws + OFF_R16;
    _Float16* pad16  = hws + OFF_PAD;
    _Float16* dwtb16 = hws + OFF_DWTB;
    _Float16* qrw16  = hws + OFF_QRW;
    _Float16* ln16   = hws + OFF_LN16;
    _Float16* kv16   = hws + OFF_KV16;
    _Float16* wT16   = hws + OFF_WT;
    _Float16* kT16   = hws + OFF_KT;
    _Float16* kvw16  = hws + OFF_KVW;
    _Float16* pw16   = hws + OFF_PW;
    _Float16* vt16   = hws + OFF_VT;
    float*    partA  = (float*)(hws + OFF_X16);   // conv partials 0,1 (x16 dead)
    float*    partB  = (float*)(hws + OFF_PART);  // conv partials 2,3
    float*    kvepart = (float*)(hws + OFF_X16);  // kve partials 0..3

    // one mega-prep launch: weight cvts + coalesced transposes + zero-fills + x cvt
    prep_kernel<<<dim3(11144), dim3(256), 0, stream>>>(
        q_w, reduce_w, kv_w, proj_w, filter_w, kve_w, x,
        qrw16, kvw16, pw16, wT16, kT16, pad16, vt16, x16);

    // fused q + r gemm (8-wave 256x128): cols<512 -> q16, >=512 -> r16
    gemm256<4><<<dim3(98, 5), dim3(512), 0, stream>>>(
        x16, qrw16, q16, 25088, 512, 512, 512, q_b, reduce_g, reduce_beta,
        reduce_b, r16);

    // DWT -> padded 30x30x512
    dwt_kernel<<<dim3(6272), dim3(128), 0, stream>>>(r16, pad16);

    // 3x3 conv split-K x4 (8-wave 256x128, depth-1 2-buffer, 3 blocks/CU)
    conv_splitk<<<dim3(400), dim3(512), 0, stream>>>(pad16, wT16, partA, partB);

    // fused conv epilogue + IDWT (writes dwtb16 and cat cols 512..639)
    conv_epi_idwt<<<dim3(6272), dim3(128), 0, stream>>>(
        partA, partB, dwtb16, cat16, filter_b, filter_g, filter_beta);

    // kve 2x2 s2 conv, split-K x4 -> fp32 partials (thin 4-wave template)
    gemm16<2, 3><<<dim3(13, 4, 4), dim3(256), 0, stream>>>(
        dwtb16, kT16, kvepart, 1568, 512, 2048, 512, nullptr, nullptr);

    // LayerNorm (fused kve partial-sum + bias) -> fp16
    ln_kernel<<<dim3(392), dim3(256), 0, stream>>>(kvepart, ln16, ln_g, ln_b, kve_b);

    // kv gemm (thin 4-wave): cols<512 -> kv16 K-half; cols>=512 -> V^T scatter
    gemm16<0, 5><<<dim3(13, 8), dim3(256), 0, stream>>>(
        ln16, kvw16, kv16, 1568, 512, 512, 1024, kv_b, vt16);

    // attention -> cat cols 0..511
    attn_mfma<<<dim3(3136), dim3(256), 0, stream>>>(q16, kv16, vt16, cat16);

    // out = cat @ proj_w.T + proj_b  (8-wave 256x128, fp32 nt store)
    gemm256<0><<<dim3(98, 4), dim3(512), 0, stream>>>(
        cat16, pw16, out, 25088, 640, 640, 512, proj_b, nullptr, nullptr,
        nullptr, nullptr);
}

// Round 12
// 360.067 us; speedup vs baseline: 1.4803x; 1.4803x over previous
//
#include <hip/hip_runtime.h>
#include <math.h>

// Problem constants: B=8, H=W=56, C=512, N=3136, c4=128, HEADS=8, hd=64, SR=2
// kv sequence length = 14*14 = 196 (padded to 224 for attention)

typedef _Float16 half8 __attribute__((ext_vector_type(8)));
typedef float f32x4 __attribute__((ext_vector_type(4)));

// ---------------- workspace layout (offsets in halves; all 16B-aligned) ----
static const size_t OFF_X16  = 0;
static const size_t OFF_Q16  = 12845056;
static const size_t OFF_CAT  = 25690112;
static const size_t OFF_R16  = 41746432;
static const size_t OFF_PAD  = 44957696;
static const size_t OFF_DWTB = 48644096;
static const size_t OFF_QRW  = 51855360;
static const size_t OFF_LN16 = 55066624;
static const size_t OFF_KV16 = 55869440;
static const size_t OFF_WT   = 57475072;
static const size_t OFF_KT   = 59834368;
static const size_t OFF_KVW  = 61145088;
static const size_t OFF_PW   = 61669376;
static const size_t OFF_VT   = 62062592;
static const size_t OFF_PART = 62980096;
// total = 75,825,152 halves = 151.7 MB

#define BN_RSQ 0.9999950000374997f
#define SCL2   0.1803368801111204f   /* 0.125 * log2(e) */
#define PART_STRIDE 3211264          /* 6272*512 floats per conv partial */
#define KVE_STRIDE  802816           /* 1568*512 floats per kve partial */

__device__ __forceinline__ void async_copy16(const _Float16* g, _Float16* l) {
    __builtin_amdgcn_global_load_lds(
        (const __attribute__((address_space(1))) void*)g,
        (__attribute__((address_space(3))) void*)l, 16, 0, 0);
}

// counted-vmcnt barriers (T4) fused in one asm (compiler can't inject vmcnt(0))
#define WAIT4_BARRIER() asm volatile("s_waitcnt vmcnt(4)\n\ts_barrier" ::: "memory")
#define WAIT3_BARRIER() asm volatile("s_waitcnt vmcnt(3)\n\ts_barrier" ::: "memory")
#define WAIT0_BARRIER() asm volatile("s_waitcnt vmcnt(0)\n\ts_barrier" ::: "memory")

// =====================================================================
// THIN 4-wave MFMA fp16 NT GEMM (128x128, BK=32) — for small GEMMs.
// ALOAD: 0 plain row-major (lda), 2 kve 2x2 stride-2 (lda = W row-stride)
// EPI:   3 = raw fp32 partial at blockIdx.z*KVE_STRIDE (split-K)
//        5 = fused kv/vt: n0<512 -> +bias->fp16 kv16; n0>=512 -> V^T scatter
// =====================================================================
template <int ALOAD, int EPI>
__global__ __launch_bounds__(256) void gemm16(
    const _Float16* __restrict__ A, const _Float16* __restrict__ W,
    void* __restrict__ outp, int M, int K, int lda, int ldc,
    const float* __restrict__ bias, void* __restrict__ outp2)
{
    __shared__ _Float16 sA[3][128 * 32];
    __shared__ _Float16 sB[3][128 * 32];
    const int t = threadIdx.x;
    const int lane = t & 63, wid = t >> 6;

    int bx = blockIdx.x, by = blockIdx.y;
    const int m0 = bx * 128, n0 = by * 128;
    const int kbase = blockIdx.z * K;

    const int sr = wid * 16 + (lane >> 2);
    const int sc = (lane & 3) * 8;
    const int stA0 = wid * 512;
    const int stA1 = 2048 + wid * 512;

    const _Float16 *aP0, *aP1;
    if constexpr (ALOAD == 0) {
        int r0 = m0 + sr;      if (r0 > M - 1) r0 = M - 1;
        int r1 = m0 + 64 + sr; if (r1 > M - 1) r1 = M - 1;
        aP0 = A + (size_t)r0 * lda + sc;
        aP1 = A + (size_t)r1 * lda + sc;
    } else {
        int m_ = m0 + sr; if (m_ > M - 1) m_ = M - 1;
        int b_ = m_ / 196, rem = m_ - b_ * 196, i_ = rem / 14, j_ = rem - i_ * 14;
        aP0 = A + ((size_t)(b_ * 784 + 2 * i_ * 28 + 2 * j_)) * 512 + sc;
        m_ = m0 + 64 + sr; if (m_ > M - 1) m_ = M - 1;
        b_ = m_ / 196; rem = m_ - b_ * 196; i_ = rem / 14; j_ = rem - i_ * 14;
        aP1 = A + ((size_t)(b_ * 784 + 2 * i_ * 28 + 2 * j_)) * 512 + sc;
    }
    const int ldw = (ALOAD == 2) ? lda : K;
    const _Float16* bP0 = W + (size_t)(n0 + sr) * ldw + sc;
    const _Float16* bP1 = W + (size_t)(n0 + 64 + sr) * ldw + sc;

    const int mw = wid & 1, nw = wid >> 1;
    const int pAoff = (mw * 64 + (lane & 15)) * 32 + (lane >> 4) * 8;
    const int pBoff = (nw * 64 + (lane & 15)) * 32 + (lane >> 4) * 8;

    f32x4 acc[4][4];
#pragma unroll
    for (int i = 0; i < 4; ++i)
#pragma unroll
        for (int j = 0; j < 4; ++j) acc[i][j] = (f32x4)(0.0f);

    auto aoff_of = [&](int k) -> int {
        if constexpr (ALOAD == 0) {
            return k;
        } else {
            int sub = k >> 9; int ky = sub >> 1, kx = sub & 1;
            return (ky * 28 + kx) * 512 + (k & 511);
        }
    };
    auto stage = [&](int ti, int buf) {
        int k = kbase + ti * 32;
        int aOff = aoff_of(k);
        async_copy16(aP0 + aOff, &sA[buf][stA0]);
        async_copy16(aP1 + aOff, &sA[buf][stA1]);
        async_copy16(bP0 + k, &sB[buf][stA0]);
        async_copy16(bP1 + k, &sB[buf][stA1]);
    };

    const int nt = K >> 5;
    stage(0, 0);
    if (nt > 1) { stage(1, 1); WAIT4_BARRIER(); }
    else        { WAIT0_BARRIER(); }

    int cur = 0;
    for (int i = 0; i < nt; ++i) {
        const _Float16* pA = &sA[cur][0] + pAoff;
        const _Float16* pB = &sB[cur][0] + pBoff;
        half8 aF[4], bF[4];
#pragma unroll
        for (int u = 0; u < 4; ++u) aF[u] = *(const half8*)(pA + u * 512);
#pragma unroll
        for (int u = 0; u < 4; ++u) bF[u] = *(const half8*)(pB + u * 512);

        const bool st = (i + 2 < nt);
        if (st) {
            int nb = cur + 2; if (nb >= 3) nb -= 3;
            stage(i + 2, nb);
        }
#pragma unroll
        for (int u = 0; u < 4; ++u)
#pragma unroll
            for (int j = 0; j < 4; ++j)
                acc[u][j] = __builtin_amdgcn_mfma_f32_16x16x32_f16(
                    aF[u], bF[j], acc[u][j], 0, 0, 0);

        if (i + 1 < nt) {
            if (st) WAIT4_BARRIER();
            else    WAIT0_BARRIER();
        }
        ++cur; if (cur == 3) cur = 0;
    }

    const int orow = m0 + mw * 64 + (lane >> 4) * 4;
    const int ocol = n0 + nw * 64 + (lane & 15);
#pragma unroll
    for (int j = 0; j < 4; ++j) {
        int col = ocol + j * 16;
        float bv = 0.0f;
        if constexpr (EPI == 5) bv = bias[col];
#pragma unroll
        for (int i = 0; i < 4; ++i) {
#pragma unroll
            for (int r = 0; r < 4; ++r) {
                int row = orow + i * 16 + r;
                if (row >= M) continue;
                float v = acc[i][j][r] + bv;
                if constexpr (EPI == 3) {
                    ((float*)outp)[(size_t)blockIdx.z * KVE_STRIDE
                                   + (size_t)row * ldc + col] = v;
                } else {   // EPI == 5
                    if (n0 >= 512) {   // V^T scatter: vt[((b*8+h)*64+d)*224+m]
                        int hd_ = col - 512;
                        int h_ = hd_ >> 6, d_ = hd_ & 63;
                        int b_ = row / 196, m_ = row - b_ * 196;
                        ((_Float16*)outp2)[((size_t)((b_ * 8 + h_) * 64 + d_)) * 224
                                           + m_] = (_Float16)v;
                    } else {
                        ((_Float16*)outp)[(size_t)row * ldc + col] = (_Float16)v;
                    }
                }
            }
        }
    }
}

// =====================================================================
// 8-WAVE 256x128 MFMA fp16 NT GEMM (BK=32, 512 threads) — R9 proven form.
// 3-buffer, counted vmcnt(3), launch_bounds(512,4) (VGPR budget 128 —
// (512,6) caps VGPR at ~85 and spills the accumulator: R11's 5x blowup).
// Waves 4(M)x2(N), per-wave 64x64 (8 ds_read feed 16 MFMA).
// EPI: 0 = +bias -> fp32 nontemporal (proj out)
//      4 = fused q/r: n0<512 -> +bias->fp16 q16; n0>=512 -> BN+ReLU->r16
// =====================================================================
template <int EPI>
__global__ __launch_bounds__(512, 4) void gemm256(
    const _Float16* __restrict__ A, const _Float16* __restrict__ W,
    void* __restrict__ outp, int M, int K, int lda, int ldc,
    const float* __restrict__ bias, const float* __restrict__ bng,
    const float* __restrict__ bnb, const float* __restrict__ bias2,
    void* __restrict__ outp2)
{
    __shared__ _Float16 sA[3][256 * 32];
    __shared__ _Float16 sB[3][128 * 32];
    const int t = threadIdx.x;
    const int lane = t & 63, wid = t >> 6;   // 0..7

    int bx = blockIdx.x, by = blockIdx.y;
    {
        int nwg = gridDim.x * gridDim.y;
        if ((nwg & 7) == 0) {            // bijective XCD-chunked remap
            int orig = by * gridDim.x + bx;
            int cs = nwg >> 3;
            int wg = (orig & 7) * cs + (orig >> 3);
            by = wg % gridDim.y;
            bx = wg / gridDim.y;
        }
    }
    const int m0 = bx * 256, n0 = by * 128;

    const int sr = wid * 16 + (lane >> 2);   // staging row
    const int sc = (lane & 3) * 8;           // staging col (halves)
    const int stO = wid * 512;

    int r0 = m0 + sr;       if (r0 > M - 1) r0 = M - 1;
    int r1 = m0 + 128 + sr; if (r1 > M - 1) r1 = M - 1;
    const _Float16* aP0 = A + (size_t)r0 * lda + sc;
    const _Float16* aP1 = A + (size_t)r1 * lda + sc;
    const _Float16* bP = W + (size_t)(n0 + sr) * K + sc;

    const int mw = wid & 3, nw = wid >> 2;   // 4(M) x 2(N)
    const int pAoff = (mw * 64 + (lane & 15)) * 32 + (lane >> 4) * 8;
    const int pBoff = (nw * 64 + (lane & 15)) * 32 + (lane >> 4) * 8;

    f32x4 acc[4][4];
#pragma unroll
    for (int u = 0; u < 4; ++u)
#pragma unroll
        for (int v = 0; v < 4; ++v) acc[u][v] = (f32x4)(0.0f);

    auto stage = [&](int ti, int buf) {
        int k = ti * 32;
        async_copy16(aP0 + k, &sA[buf][stO]);
        async_copy16(aP1 + k, &sA[buf][4096 + stO]);
        async_copy16(bP + k, &sB[buf][stO]);
    };

    const int nt = K >> 5;
    stage(0, 0);
    stage(1, 1);
    WAIT3_BARRIER();

    int cur = 0;
    for (int i = 0; i < nt; ++i) {
        const _Float16* pA = &sA[cur][0] + pAoff;
        const _Float16* pB = &sB[cur][0] + pBoff;
        half8 aF[4], bF[4];
#pragma unroll
        for (int u = 0; u < 4; ++u) aF[u] = *(const half8*)(pA + u * 512);
#pragma unroll
        for (int v = 0; v < 4; ++v) bF[v] = *(const half8*)(pB + v * 512);

        const bool st = (i + 2 < nt);
        if (st) {
            int nb = cur + 2; if (nb >= 3) nb -= 3;
            stage(i + 2, nb);
        }
#pragma unroll
        for (int u = 0; u < 4; ++u)
#pragma unroll
            for (int v = 0; v < 4; ++v)
                acc[u][v] = __builtin_amdgcn_mfma_f32_16x16x32_f16(
                    aF[u], bF[v], acc[u][v], 0, 0, 0);

        if (i + 1 < nt) {
            if (st) WAIT3_BARRIER();
            else    WAIT0_BARRIER();
        }
        ++cur; if (cur == 3) cur = 0;
    }

    // epilogue: wave covers 64M x 64N; C/D layout col=lane&15, row=(lane>>4)*4+reg
    const int orow = m0 + mw * 64 + (lane >> 4) * 4;
    const int ocol = n0 + nw * 64 + (lane & 15);
#pragma unroll
    for (int v = 0; v < 4; ++v) {
        int col = ocol + v * 16;
        float bv, g = 0.0f, b2 = 0.0f;
        if constexpr (EPI == 4) {
            if (n0 >= 512) {           // r path (block-uniform branch)
                bv = bias2[col - 512];
                g = bng[col - 512] * BN_RSQ;
                b2 = bnb[col - 512];
            } else {
                bv = bias[col];
            }
        } else {
            bv = bias[col];
        }
#pragma unroll
        for (int u = 0; u < 4; ++u) {
#pragma unroll
            for (int r = 0; r < 4; ++r) {
                int row = orow + u * 16 + r;
                if (row >= M) continue;
                float v2 = acc[u][v][r] + bv;
                if constexpr (EPI == 0) {
                    __builtin_nontemporal_store(
                        v2, (float*)outp + (size_t)row * ldc + col);
                } else {   // EPI == 4
                    if (n0 >= 512) {
                        v2 = fmaxf(v2 * g + b2, 0.0f);
                        ((_Float16*)outp2)[(size_t)row * 128 + (col - 512)] =
                            (_Float16)v2;
                    } else {
                        ((_Float16*)outp)[(size_t)row * ldc + col] = (_Float16)v2;
                    }
                }
            }
        }
    }
}

// =====================================================================
// 8-wave 256x128 conv3x3 split-K partial GEMM — R9 proven form (3-buffer,
// counted vmcnt(3), launch_bounds(512,4)). The R11 2-buffer/(512,6) probe
// spilled the accumulator (VGPR cap ~85 at 6 waves/SIMD) -> 339MB scratch
// writes, 5x slower. This kernel is register-residency-bound at 1 block/CU
// (8 waves x ~256 VGPR); treat as converged.
// grid 400 linear (25 m x 4 n x 4 z), XCD-chunked swizzle (400 = 8*50).
// =====================================================================
__global__ __launch_bounds__(512, 4) void conv_splitk(
    const _Float16* __restrict__ A, const _Float16* __restrict__ W,
    float* __restrict__ partA, float* __restrict__ partB)
{
    __shared__ _Float16 sA[3][256 * 32];
    __shared__ _Float16 sB[3][128 * 32];
    const int t = threadIdx.x;
    const int lane = t & 63, wid = t >> 6;   // 0..7

    // bijective XCD-chunked remap: 400 = 8 * 50
    int orig = blockIdx.x;
    int wg = (orig & 7) * 50 + (orig >> 3);
    int bx = wg % 25;  int c = wg / 25;    // c in 0..15
    int by = c & 3,    bz = c >> 2;

    const int m0 = bx * 256, n0 = by * 128;
    const int kbase = bz * 1152;

    const int sr = wid * 16 + (lane >> 2);
    const int sc = (lane & 3) * 8;
    const int stO = wid * 512;

    int m_ = m0 + sr; if (m_ > 6271) m_ = 6271;
    int b_ = m_ / 784, rem = m_ - b_ * 784, y_ = rem / 28, x_ = rem - y_ * 28;
    const _Float16* aP0 = A + ((size_t)(b_ * 900 + (y_ + 1) * 30 + (x_ + 1))) * 512 + sc;
    m_ = m0 + 128 + sr; if (m_ > 6271) m_ = 6271;
    b_ = m_ / 784; rem = m_ - b_ * 784; y_ = rem / 28; x_ = rem - y_ * 28;
    const _Float16* aP1 = A + ((size_t)(b_ * 900 + (y_ + 1) * 30 + (x_ + 1))) * 512 + sc;
    const _Float16* bP = W + (size_t)(n0 + sr) * 4608 + sc;

    const int mw = wid & 3, nw = wid >> 2;
    const int pAoff = (mw * 64 + (lane & 15)) * 32 + (lane >> 4) * 8;
    const int pBoff = (nw * 64 + (lane & 15)) * 32 + (lane >> 4) * 8;

    f32x4 acc[4][4];
#pragma unroll
    for (int u = 0; u < 4; ++u)
#pragma unroll
        for (int v = 0; v < 4; ++v) acc[u][v] = (f32x4)(0.0f);

    auto aoff_of = [&](int k) -> int {
        int sub = k >> 9; int s3 = sub / 3;
        int dy = s3 - 1, dx = sub - s3 * 3 - 1;
        return (dy * 30 + dx) * 512 + (k & 511);
    };
    auto stage = [&](int ti, int buf) {
        int k = kbase + ti * 32;
        int aOff = aoff_of(k);
        async_copy16(aP0 + aOff, &sA[buf][stO]);
        async_copy16(aP1 + aOff, &sA[buf][4096 + stO]);
        async_copy16(bP + k, &sB[buf][stO]);
    };

    const int nt = 36;   // 1152/32
    stage(0, 0);
    stage(1, 1);
    WAIT3_BARRIER();

    int cur = 0;
    for (int i = 0; i < nt; ++i) {
        const _Float16* pA = &sA[cur][0] + pAoff;
        const _Float16* pB = &sB[cur][0] + pBoff;
        half8 aF[4], bF[4];
#pragma unroll
        for (int u = 0; u < 4; ++u) aF[u] = *(const half8*)(pA + u * 512);
#pragma unroll
        for (int v = 0; v < 4; ++v) bF[v] = *(const half8*)(pB + v * 512);

        const bool st = (i + 2 < nt);
        if (st) {
            int nb = cur + 2; if (nb >= 3) nb -= 3;
            stage(i + 2, nb);
        }
#pragma unroll
        for (int u = 0; u < 4; ++u)
#pragma unroll
            for (int v = 0; v < 4; ++v)
                acc[u][v] = __builtin_amdgcn_mfma_f32_16x16x32_f16(
                    aF[u], bF[v], acc[u][v], 0, 0, 0);

        if (i + 1 < nt) {
            if (st) WAIT3_BARRIER();
            else    WAIT0_BARRIER();
        }
        ++cur; if (cur == 3) cur = 0;
    }

    float* dst = (bz < 2) ? (partA + (size_t)bz * PART_STRIDE)
                          : (partB + (size_t)(bz - 2) * PART_STRIDE);
    const int orow = m0 + mw * 64 + (lane >> 4) * 4;
    const int ocol = n0 + nw * 64 + (lane & 15);
#pragma unroll
    for (int v = 0; v < 4; ++v) {
#pragma unroll
        for (int u = 0; u < 4; ++u) {
#pragma unroll
            for (int r = 0; r < 4; ++r) {
                int row = orow + u * 16 + r;
                if (row < 6272)
                    dst[(size_t)row * 512 + ocol + v * 16] = acc[u][v][r];
            }
        }
    }
}

// =====================================================================
// FUSED conv epilogue + Haar IDWT. One block per output pixel (6272),
// 128 threads. Writes dwtb16 + IDWT -> cat cols 512..639 (nt).
// =====================================================================
__global__ __launch_bounds__(128) void conv_epi_idwt(
    const float* __restrict__ pA, const float* __restrict__ pB,
    _Float16* __restrict__ dwtb, _Float16* __restrict__ cat,
    const float* __restrict__ bias, const float* __restrict__ bng,
    const float* __restrict__ bnb)
{
    int p = blockIdx.x;              // b*784 + i*28 + j
    int b = p / 784; int rem = p - b * 784;
    int i = rem / 28;  int j = rem - i * 28;
    int c = threadIdx.x;
    size_t base = (size_t)p * 512;
    _Float16 g16[4];
#pragma unroll
    for (int g = 0; g < 4; ++g) {
        int ch = g * 128 + c;
        float s = (pA[base + ch] + pA[PART_STRIDE + base + ch])
                + (pB[base + ch] + pB[PART_STRIDE + base + ch]);
        float v = (s + bias[ch]) * (bng[ch] * BN_RSQ) + bnb[ch];
        g16[g] = (_Float16)fmaxf(v, 0.0f);
        dwtb[base + ch] = g16[g];
    }
    _Float16 ll = g16[0], hl = g16[1], lh = g16[2], hh = g16[3];
    _Float16 h = (_Float16)0.5f;
    _Float16 p1 = (((ll - hl) - lh) + hh) * h;
    _Float16 p2 = (((ll - hl) + lh) - hh) * h;
    _Float16 p3 = (((ll + hl) - lh) - hh) * h;
    _Float16 p4 = (((ll + hl) + lh) + hh) * h;
    int y = 2 * i, x = 2 * j;
    size_t rb = (size_t)b * 3136;
    __builtin_nontemporal_store(p1, &cat[(rb + (size_t)y * 56 + x) * 640 + 512 + c]);
    __builtin_nontemporal_store(p3, &cat[(rb + (size_t)y * 56 + x + 1) * 640 + 512 + c]);
    __builtin_nontemporal_store(p2, &cat[(rb + (size_t)(y + 1) * 56 + x) * 640 + 512 + c]);
    __builtin_nontemporal_store(p4, &cat[(rb + (size_t)(y + 1) * 56 + x + 1) * 640 + 512 + c]);
}

// =====================================================================
// MEGA-PREP v2: coalesced transposes + weight cvts + zero-fills + x cvt.
//  [0,128)       q_w cvt -> qrw16             (32768 x8)
//  [128,160)     reduce_w cvt -> qrw16+262144 (8192 x8)
//  [160,416)     kv_w cvt -> kvw16            (65536 x8)
//  [416,576)     proj_w cvt -> pw16           (40960 x8)
//  [576,1600)    filter transpose (512n x 512ci, 9 elems/thread)
//  [1600,2624)   kve transpose    (512n x 512ci, float4/thread)
//  [2624,4424)   zero pad16                   (460800 x8)
//  [4424,4872)   zero vt16                    (114688 x8)
//  [4872,11144)  x cvt -> x16                 (1605632 x8)
// =====================================================================
__device__ __forceinline__ void cvt8_at(
    const float* __restrict__ s, _Float16* __restrict__ d, int i)
{
    const float4* sp = (const float4*)(s + (size_t)i * 8);
    float4 a = sp[0], b = sp[1];
    half8 h;
    h[0] = (_Float16)a.x; h[1] = (_Float16)a.y; h[2] = (_Float16)a.z; h[3] = (_Float16)a.w;
    h[4] = (_Float16)b.x; h[5] = (_Float16)b.y; h[6] = (_Float16)b.z; h[7] = (_Float16)b.w;
    *(half8*)(d + (size_t)i * 8) = h;
}

__global__ __launch_bounds__(256) void prep_kernel(
    const float* __restrict__ qw, const float* __restrict__ rw,
    const float* __restrict__ kvw, const float* __restrict__ pw,
    const float* __restrict__ fw, const float* __restrict__ kw,
    const float* __restrict__ x,
    _Float16* __restrict__ qrw16, _Float16* __restrict__ kvw16,
    _Float16* __restrict__ pw16, _Float16* __restrict__ wT,
    _Float16* __restrict__ kT, _Float16* __restrict__ pad,
    _Float16* __restrict__ vt, _Float16* __restrict__ x16)
{
    int bid = blockIdx.x, tid = threadIdx.x;
    if (bid < 128) {
        cvt8_at(qw, qrw16, bid * 256 + tid);
    } else if (bid < 160) {
        cvt8_at(rw, qrw16 + 262144, (bid - 128) * 256 + tid);
    } else if (bid < 416) {
        cvt8_at(kvw, kvw16, (bid - 160) * 256 + tid);
    } else if (bid < 576) {
        cvt8_at(pw, pw16, (bid - 416) * 256 + tid);
    } else if (bid < 1600) {
        // filter transpose: wT[n*4608 + s*512 + ci] = fw[n*4608 + ci*9 + s]
        int id = (bid - 576) * 256 + tid;      // 262144 = 512n x 512ci
        int n = id >> 9, ci = id & 511;
        const float* src = fw + (size_t)n * 4608 + ci * 9;
        _Float16* dstp = wT + (size_t)n * 4608 + ci;
#pragma unroll
        for (int s = 0; s < 9; ++s)
            dstp[s * 512] = (_Float16)src[s];
    } else if (bid < 2624) {
        // kve transpose: kT[n*2048 + s*512 + ci] = kw[n*2048 + ci*4 + s]
        int id = (bid - 1600) * 256 + tid;     // 262144
        int n = id >> 9, ci = id & 511;
        float4 kv4 = *(const float4*)(kw + ((size_t)n << 11) + (ci << 2));
        _Float16* dstp = kT + ((size_t)n << 11) + ci;
        dstp[0]    = (_Float16)kv4.x;
        dstp[512]  = (_Float16)kv4.y;
        dstp[1024] = (_Float16)kv4.z;
        dstp[1536] = (_Float16)kv4.w;
    } else if (bid < 4424) {
        int i = (bid - 2624) * 256 + tid;
        *(float4*)(pad + (size_t)i * 8) = make_float4(0.f, 0.f, 0.f, 0.f);
    } else if (bid < 4872) {
        int i = (bid - 4424) * 256 + tid;
        *(float4*)(vt + (size_t)i * 8) = make_float4(0.f, 0.f, 0.f, 0.f);
    } else {
        cvt8_at(x, x16, (bid - 4872) * 256 + tid);
    }
}

// =====================================================================
// Haar DWT: rbuf16 (B,56,56,128 NHWC fp16) -> padded (B,30,30,512 NHWC fp16)
// =====================================================================
__global__ __launch_bounds__(128) void dwt_kernel(
    const _Float16* __restrict__ r, _Float16* __restrict__ pad)
{
    int bid = blockIdx.x;            // b*784 + i*28 + j
    int b = bid / 784; int rem = bid - b * 784;
    int i = rem / 28;  int j = rem - i * 28;
    int c = threadIdx.x;
    int y = 2 * i, x = 2 * j;
    size_t base = (size_t)b * 3136;
    _Float16 f1 = r[(base + (size_t)y * 56 + x) * 128 + c];
    _Float16 f2 = r[(base + (size_t)(y + 1) * 56 + x) * 128 + c];
    _Float16 f3 = r[(base + (size_t)y * 56 + (x + 1)) * 128 + c];
    _Float16 f4 = r[(base + (size_t)(y + 1) * 56 + (x + 1)) * 128 + c];
    _Float16 h = (_Float16)0.5f;
    _Float16 x1 = f1 * h, x2 = f2 * h, x3 = f3 * h, x4 = f4 * h;
    _Float16 ll = ((x1 + x2) + x3) + x4;
    _Float16 hl = (((-x1) - x2) + x3) + x4;
    _Float16 lh = (((-x1) + x2) - x3) + x4;
    _Float16 hh = ((x1 - x2) - x3) + x4;
    size_t ob = ((size_t)b * 900 + (size_t)(i + 1) * 30 + (j + 1)) * 512;
    pad[ob + c]       = ll;
    pad[ob + 128 + c] = hl;
    pad[ob + 256 + c] = lh;
    pad[ob + 384 + c] = hh;
}

// =====================================================================
// LayerNorm over C=512, fused kve split-K reduction. One wave per row.
// =====================================================================
__global__ __launch_bounds__(256) void ln_kernel(
    const float* __restrict__ part, _Float16* __restrict__ o,
    const float* __restrict__ g, const float* __restrict__ bta,
    const float* __restrict__ kvb)
{
    int wave = threadIdx.x >> 6;
    int lane = threadIdx.x & 63;
    int row = blockIdx.x * 4 + wave;            // 392*4 = 1568
    int c = lane * 8;
    const float* rp = part + (size_t)row * 512 + c;
    float v[8];
#pragma unroll
    for (int i = 0; i < 8; i += 4) {
        float4 a0 = *(const float4*)(rp + i);
        float4 a1 = *(const float4*)(rp + KVE_STRIDE + i);
        float4 a2 = *(const float4*)(rp + 2 * KVE_STRIDE + i);
        float4 a3 = *(const float4*)(rp + 3 * KVE_STRIDE + i);
        v[i + 0] = (a0.x + a1.x) + (a2.x + a3.x) + kvb[c + i + 0];
        v[i + 1] = (a0.y + a1.y) + (a2.y + a3.y) + kvb[c + i + 1];
        v[i + 2] = (a0.z + a1.z) + (a2.z + a3.z) + kvb[c + i + 2];
        v[i + 3] = (a0.w + a1.w) + (a2.w + a3.w) + kvb[c + i + 3];
    }
    float s = ((v[0] + v[1]) + (v[2] + v[3])) + ((v[4] + v[5]) + (v[6] + v[7]));
#pragma unroll
    for (int off = 32; off; off >>= 1) s += __shfl_xor(s, off);
    float mu = s * (1.0f / 512.0f);
    float sq = 0.0f;
#pragma unroll
    for (int i = 0; i < 8; ++i) { v[i] -= mu; sq += v[i] * v[i]; }
#pragma unroll
    for (int off = 32; off; off >>= 1) sq += __shfl_xor(sq, off);
    float inv = 1.0f / sqrtf(sq * (1.0f / 512.0f) + 1e-5f);
    half8 hv;
#pragma unroll
    for (int i = 0; i < 8; ++i) hv[i] = (_Float16)(v[i] * inv * g[c + i] + bta[c + i]);
    *(half8*)(o + (size_t)row * 512 + c) = hv;
}

// =====================================================================
// MFMA flash attention. Block = (b, h, 64 q-rows); 4 waves x 16 q-rows.
// Unnormalized softmax (scores tiny), one reduction at the end.
// s_setprio(1) around MFMA clusters (T5).
// =====================================================================
__global__ __launch_bounds__(256) void attn_mfma(
    const _Float16* __restrict__ q, const _Float16* __restrict__ kv,
    const _Float16* __restrict__ vt, _Float16* __restrict__ cat)
{
    __shared__ _Float16 sK[64][72];    // K[m][d]
    __shared__ _Float16 sVT[64][72];   // V^T[d][m-chunk]
    __shared__ _Float16 sP[4][16][40]; // per-wave P round-trip
    int bid = blockIdx.x;
    int qt = bid % 49;
    int h  = (bid / 49) & 7;
    int b  = bid / 392;
    int n0 = qt * 64;
    int t = threadIdx.x, lane = t & 63, wid = t >> 6;
    int quad = lane >> 4, l16 = lane & 15;

    const _Float16* qp = q + ((size_t)(b * 3136 + n0 + wid * 16 + l16)) * 512
                           + h * 64 + quad * 8;
    half8 aQ0 = *(const half8*)qp;
    half8 aQ1 = *(const half8*)(qp + 32);

    f32x4 oacc[4];
#pragma unroll
    for (int i = 0; i < 4; ++i) oacc[i] = (f32x4)(0.0f);
    float lsum[4] = {0.f, 0.f, 0.f, 0.f};

    const _Float16* vtb = vt + ((size_t)((b * 8 + h) * 64)) * 224;

    for (int c0 = 0; c0 < 224; c0 += 64) {
        __syncthreads();
#pragma unroll
        for (int it = 0; it < 2; ++it) {
            int slot = t + 256 * it;
            int row = slot >> 3, c8 = (slot & 7) * 8;
            int m = c0 + row; if (m > 195) m = 195;
            *(half8*)&sK[row][c8] =
                *(const half8*)(kv + ((size_t)(b * 196 + m)) * 1024 + h * 64 + c8);
        }
#pragma unroll
        for (int it = 0; it < 2; ++it) {
            int slot = t + 256 * it;
            int row = slot >> 3, c8 = (slot & 7) * 8;
            *(half8*)&sVT[row][c8] =
                *(const half8*)(vtb + (size_t)row * 224 + c0 + c8);
        }
        __syncthreads();

#pragma unroll
        for (int sc = 0; sc < 64; sc += 32) {
            half8 bk00 = *(const half8*)&sK[sc + l16][quad * 8];
            half8 bk01 = *(const half8*)&sK[sc + l16][32 + quad * 8];
            half8 bk10 = *(const half8*)&sK[sc + 16 + l16][quad * 8];
            half8 bk11 = *(const half8*)&sK[sc + 16 + l16][32 + quad * 8];
            f32x4 s0 = (f32x4)(0.0f), s1 = (f32x4)(0.0f);
            __builtin_amdgcn_s_setprio(1);
            s0 = __builtin_amdgcn_mfma_f32_16x16x32_f16(aQ0, bk00, s0, 0, 0, 0);
            s0 = __builtin_amdgcn_mfma_f32_16x16x32_f16(aQ1, bk01, s0, 0, 0, 0);
            s1 = __builtin_amdgcn_mfma_f32_16x16x32_f16(aQ0, bk10, s1, 0, 0, 0);
            s1 = __builtin_amdgcn_mfma_f32_16x16x32_f16(aQ1, bk11, s1, 0, 0, 0);
            __builtin_amdgcn_s_setprio(0);

            int col0 = c0 + sc + l16;
            float msk0 = (col0 < 196) ? 0.0f : -INFINITY;
            float msk1 = (col0 + 16 < 196) ? 0.0f : -INFINITY;
            float p0[4], p1[4];
#pragma unroll
            for (int r = 0; r < 4; ++r) {
                p0[r] = exp2f(s0[r] * SCL2 + msk0);
                p1[r] = exp2f(s1[r] * SCL2 + msk1);
                lsum[r] += p0[r] + p1[r];
            }
#pragma unroll
            for (int r = 0; r < 4; ++r) {
                sP[wid][quad * 4 + r][l16]      = (_Float16)p0[r];
                sP[wid][quad * 4 + r][16 + l16] = (_Float16)p1[r];
            }
            half8 aP = *(const half8*)&sP[wid][l16][quad * 8];
            half8 bv0 = *(const half8*)&sVT[l16][sc + quad * 8];
            half8 bv1 = *(const half8*)&sVT[16 + l16][sc + quad * 8];
            half8 bv2 = *(const half8*)&sVT[32 + l16][sc + quad * 8];
            half8 bv3 = *(const half8*)&sVT[48 + l16][sc + quad * 8];
            __builtin_amdgcn_s_setprio(1);
            oacc[0] = __builtin_amdgcn_mfma_f32_16x16x32_f16(aP, bv0, oacc[0], 0, 0, 0);
            oacc[1] = __builtin_amdgcn_mfma_f32_16x16x32_f16(aP, bv1, oacc[1], 0, 0, 0);
            oacc[2] = __builtin_amdgcn_mfma_f32_16x16x32_f16(aP, bv2, oacc[2], 0, 0, 0);
            oacc[3] = __builtin_amdgcn_mfma_f32_16x16x32_f16(aP, bv3, oacc[3], 0, 0, 0);
            __builtin_amdgcn_s_setprio(0);
        }
    }

    float inv[4];
#pragma unroll
    for (int r = 0; r < 4; ++r) {
        float s = lsum[r];
        s += __shfl_xor(s, 1);
        s += __shfl_xor(s, 2);
        s += __shfl_xor(s, 4);
        s += __shfl_xor(s, 8);
        inv[r] = 1.0f / s;
    }
#pragma unroll
    for (int r = 0; r < 4; ++r) {
        size_t rowoff = ((size_t)(b * 3136 + n0 + wid * 16 + quad * 4 + r)) * 640
                        + h * 64 + l16;
#pragma unroll
        for (int tv = 0; tv < 4; ++tv)
            cat[rowoff + tv * 16] = (_Float16)(oacc[tv][r] * inv[r]);
    }
}

// =====================================================================
extern "C" void kernel_launch(void* const* d_in, const int* in_sizes, int n_in,
                              void* d_out, int out_size, void* d_ws, size_t ws_size,
                              hipStream_t stream)
{
    const float* x           = (const float*)d_in[0];
    const float* reduce_w    = (const float*)d_in[3];
    const float* reduce_b    = (const float*)d_in[4];
    const float* reduce_g    = (const float*)d_in[5];
    const float* reduce_beta = (const float*)d_in[6];
    const float* filter_w    = (const float*)d_in[7];
    const float* filter_b    = (const float*)d_in[8];
    const float* filter_g    = (const float*)d_in[9];
    const float* filter_beta = (const float*)d_in[10];
    const float* q_w         = (const float*)d_in[11];
    const float* q_b         = (const float*)d_in[12];
    const float* ln_g        = (const float*)d_in[13];
    const float* ln_b        = (const float*)d_in[14];
    const float* kv_w        = (const float*)d_in[15];
    const float* kv_b        = (const float*)d_in[16];
    const float* kve_w       = (const float*)d_in[17];
    const float* kve_b       = (const float*)d_in[18];
    const float* proj_w      = (const float*)d_in[19];
    const float* proj_b      = (const float*)d_in[20];
    float* out = (float*)d_out;
    _Float16* hws = (_Float16*)d_ws;

    _Float16* x16    = hws + OFF_X16;
    _Float16* q16    = hws + OFF_Q16;
    _Float16* cat16  = hws + OFF_CAT;
    _Float16* r16    = hws + OFF_R16;
    _Float16* pad16  = hws + OFF_PAD;
    _Float16* dwtb16 = hws + OFF_DWTB;
    _Float16* qrw16  = hws + OFF_QRW;
    _Float16* ln16   = hws + OFF_LN16;
    _Float16* kv16   = hws + OFF_KV16;
    _Float16* wT16   = hws + OFF_WT;
    _Float16* kT16   = hws + OFF_KT;
    _Float16* kvw16  = hws + OFF_KVW;
    _Float16* pw16   = hws + OFF_PW;
    _Float16* vt16   = hws + OFF_VT;
    float*    partA  = (float*)(hws + OFF_X16);   // conv partials 0,1 (x16 dead)
    float*    partB  = (float*)(hws + OFF_PART);  // conv partials 2,3
    float*    kvepart = (float*)(hws + OFF_X16);  // kve partials 0..3

    // one mega-prep launch: weight cvts + coalesced transposes + zero-fills + x cvt
    prep_kernel<<<dim3(11144), dim3(256), 0, stream>>>(
        q_w, reduce_w, kv_w, proj_w, filter_w, kve_w, x,
        qrw16, kvw16, pw16, wT16, kT16, pad16, vt16, x16);

    // fused q + r gemm (8-wave 256x128): cols<512 -> q16, >=512 -> r16
    gemm256<4><<<dim3(98, 5), dim3(512), 0, stream>>>(
        x16, qrw16, q16, 25088, 512, 512, 512, q_b, reduce_g, reduce_beta,
        reduce_b, r16);

    // DWT -> padded 30x30x512
    dwt_kernel<<<dim3(6272), dim3(128), 0, stream>>>(r16, pad16);

    // 3x3 conv split-K x4 (8-wave 256x128, 3-buffer vmcnt(3), R9 form)
    conv_splitk<<<dim3(400), dim3(512), 0, stream>>>(pad16, wT16, partA, partB);

    // fused conv epilogue + IDWT (writes dwtb16 and cat cols 512..639)
    conv_epi_idwt<<<dim3(6272), dim3(128), 0, stream>>>(
        partA, partB, dwtb16, cat16, filter_b, filter_g, filter_beta);

    // kve 2x2 s2 conv, split-K x4 -> fp32 partials (thin 4-wave template)
    gemm16<2, 3><<<dim3(13, 4, 4), dim3(256), 0, stream>>>(
        dwtb16, kT16, kvepart, 1568, 512, 2048, 512, nullptr, nullptr);

    // LayerNorm (fused kve partial-sum + bias) -> fp16
    ln_kernel<<<dim3(392), dim3(256), 0, stream>>>(kvepart, ln16, ln_g, ln_b, kve_b);

    // kv gemm (thin 4-wave): cols<512 -> kv16 K-half; cols>=512 -> V^T scatter
    gemm16<0, 5><<<dim3(13, 8), dim3(256), 0, stream>>>(
        ln16, kvw16, kv16, 1568, 512, 512, 1024, kv_b, vt16);

    // attention -> cat cols 0..511
    attn_mfma<<<dim3(3136), dim3(256), 0, stream>>>(q16, kv16, vt16, cat16);

    // out = cat @ proj_w.T + proj_b  (8-wave 256x128, fp32 nt store)
    gemm256<0><<<dim3(98, 4), dim3(512), 0, stream>>>(
        cat16, pw16, out, 25088, 640, 640, 512, proj_b, nullptr, nullptr,
        nullptr, nullptr);
}